// Round 5
// baseline (228.803 us; speedup 1.0000x reference)
//
#include <hip/hip_runtime.h>
#include <hip/hip_bf16.h>

// Problem constants (fixed by setup_inputs)
#define B   8
#define T   2048
#define C   256      // channels; 64 float4
#define L   32       // query rows / label count
#define DQ  512
#define NW  2017     // T - window_size + 1
#define NK  8        // num_chunks
#define CIC 4        // window/num_chunks
#define WT  16       // w-tile per block
#define SROWS (WT + (NK-1)*CIC)   // 44 pooled rows per tile
#define LROWS (SROWS + 3)         // 47 label rows per tile (w0 .. w0+46)

typedef float nfloat4 __attribute__((ext_vector_type(4)));  // native vec for nt-store

// ---------------- Kernel 1: enc1/enc2 = query @ W{1,2} + b{1,2} ----------------
// (unchanged)
__global__ __launch_bounds__(256) void enc_kernel(
    const float* __restrict__ query, const float* __restrict__ W1,
    const float* __restrict__ b1, const float* __restrict__ W2,
    const float* __restrict__ b2, float* __restrict__ enc1,
    float* __restrict__ enc2) {
  const int lg = blockIdx.x, b = blockIdx.y, cs = blockIdx.z;
  const int tid = threadIdx.x;
  const int tx = tid & 63;    // channel within 64-slice
  const int dq = tid >> 6;    // d-quarter (wave-uniform)
  const int c = cs * 64 + tx;
  __shared__ float4 qs4[4][DQ / 4];        // [j][g] 8 KB
  __shared__ float red[2][4][4][64];       // [e][dq][j][tx] 8 KB

  const float4* q4 = (const float4*)(query + ((size_t)b * L + lg * 4) * DQ);
  for (int i = tid; i < 4 * (DQ / 4); i += 256) {
    const int j = i >> 7, g = i & 127;
    qs4[j][g] = q4[j * (DQ / 4) + g];
  }
  __syncthreads();

  float a1[4] = {0.f, 0.f, 0.f, 0.f};
  float a2[4] = {0.f, 0.f, 0.f, 0.f};
  const int g0 = dq * 32;
#pragma unroll 4
  for (int gg = 0; gg < 32; ++gg) {
    const int g = g0 + gg;
    const float4 q0 = qs4[0][g], q1 = qs4[1][g], q2 = qs4[2][g], q3 = qs4[3][g];
    const float* wp1 = W1 + (size_t)(4 * g) * C + c;
    const float* wp2 = W2 + (size_t)(4 * g) * C + c;
    const float w10 = wp1[0], w11 = wp1[C], w12 = wp1[2 * C], w13 = wp1[3 * C];
    const float w20 = wp2[0], w21 = wp2[C], w22 = wp2[2 * C], w23 = wp2[3 * C];
    a1[0] = fmaf(q0.x, w10, fmaf(q0.y, w11, fmaf(q0.z, w12, fmaf(q0.w, w13, a1[0]))));
    a1[1] = fmaf(q1.x, w10, fmaf(q1.y, w11, fmaf(q1.z, w12, fmaf(q1.w, w13, a1[1]))));
    a1[2] = fmaf(q2.x, w10, fmaf(q2.y, w11, fmaf(q2.z, w12, fmaf(q2.w, w13, a1[2]))));
    a1[3] = fmaf(q3.x, w10, fmaf(q3.y, w11, fmaf(q3.z, w12, fmaf(q3.w, w13, a1[3]))));
    a2[0] = fmaf(q0.x, w20, fmaf(q0.y, w21, fmaf(q0.z, w22, fmaf(q0.w, w23, a2[0]))));
    a2[1] = fmaf(q1.x, w20, fmaf(q1.y, w21, fmaf(q1.z, w22, fmaf(q1.w, w23, a2[1]))));
    a2[2] = fmaf(q2.x, w20, fmaf(q2.y, w21, fmaf(q2.z, w22, fmaf(q2.w, w23, a2[2]))));
    a2[3] = fmaf(q3.x, w20, fmaf(q3.y, w21, fmaf(q3.z, w22, fmaf(q3.w, w23, a2[3]))));
  }
#pragma unroll
  for (int j = 0; j < 4; ++j) {
    red[0][dq][j][tx] = a1[j];
    red[1][dq][j][tx] = a2[j];
  }
  __syncthreads();

  for (int o = tid; o < 512; o += 256) {
    const int e = o >> 8, j = (o >> 6) & 3, t = o & 63;
    const float v = red[e][0][j][t] + red[e][1][j][t] +
                    red[e][2][j][t] + red[e][3][j][t];
    const int cc = cs * 64 + t;
    const size_t off = ((size_t)b * L + lg * 4 + j) * C + cc;
    if (e == 0) enc1[off] = v + b1[cc];
    else        enc2[off] = v + b2[cc];
  }
}

// ---------------- Kernel 2 (fused): labels + majority + pooling + modulated out ----
// Round-5 = Round-4 design, hardened (dropped readfirstlane; wv is already
// wave-uniform). Label matmul transposed to lane=row / wave=8-labels:
//  * enc1 operand is wave-uniform per (label,chan) -> scalar loads, free.
//  * vis read from LDS full-width (1 KB/instr, XOR-swizzled) instead of 32 B
//    broadcasts: label-phase LDS pipe time drops ~6x.
//  * channel dim staged in two 24 KB halves: LDS union ~45.4 KB -> 3 blocks/CU.
// Numerics: per-(row,label) dot = same 8x 32-ch fmaf nests, same even+odd pair
// adds, same ((p0+p1)+p2)+p3 final order, same ascending strict-> argmax as the
// verified kernel -> bit-identical labels.
__global__ __launch_bounds__(256) void fused_kernel(
    const float* __restrict__ vis, const float* __restrict__ enc1,
    const float* __restrict__ enc2, float* __restrict__ out) {
  const int b = blockIdx.y;
  const int w0 = blockIdx.x * WT;
  const int tid = threadIdx.x;
  const int lane = tid & 63;
  const int wv = tid >> 6;              // wave id, wave-uniform

  // LDS union:
  //   label phase: raw2[48][32] float4 @0 (24576 B) + pacc2[48][32] float @24576 (6144 B)
  //   pool phase:  S4[44][64] float4 @0 (45056 B) overlays both (barrier-separated)
  __shared__ alignas(16) char smem[45056];
  float4* raw2 = (float4*)smem;                   // [48][32], col XOR-swizzled
  float* pacc2 = (float*)(smem + 24576);          // [48][32], col XOR-swizzled
  float4* S4 = (float4*)smem;                     // [44][64]
  __shared__ int lbl[LROWS];
  __shared__ int slbl[SROWS];

  const float4* vb = (const float4*)(vis + (size_t)b * T * C);
  const int myrow = lane < LROWS ? lane : (LROWS - 1);   // lanes 47-63 duplicate

  // enc1 base for this wave's 8 labels — wave-uniform => scalar loads
  const float* __restrict__ e1u = enc1 + ((size_t)b * L + wv * 8) * C;

  float run[8], cur[8];

  // ---- label phase: two channel-halves staged through 24 KB LDS ----
#pragma unroll 1
  for (int half = 0; half < 2; ++half) {
    if (half) __syncthreads();   // all reads of previous half done before overwrite
    for (int i = tid; i < LROWS * 32; i += 256) {
      const int t = i >> 5, col = i & 31;
      int tg = w0 + t;
      tg = tg > (T - 1) ? (T - 1) : tg;          // clamp (matches verified clamp)
      raw2[t * 32 + (col ^ (t & 7))] = vb[(size_t)tg * 64 + half * 32 + col];
    }
    __syncthreads();
#pragma unroll
    for (int c8 = 0; c8 < 4; ++c8) {             // 32-ch chunk within half
      float4 v[8];
#pragma unroll
      for (int j = 0; j < 8; ++j)
        v[j] = raw2[myrow * 32 + ((c8 * 8 + j) ^ (myrow & 7))];
      const int cp = half * 2 + (c8 >> 1);       // chunk-pair index 0..3
      const bool even = (c8 & 1) == 0;
#pragma unroll
      for (int q = 0; q < 8; ++q) {
        const float* eq = e1u + q * C + (half * 4 + c8) * 32;  // uniform addr
        float a = 0.f;
#pragma unroll
        for (int j = 0; j < 8; ++j) {
          const float4 vv = v[j];
          a = fmaf(vv.x, eq[4 * j + 0],
              fmaf(vv.y, eq[4 * j + 1],
              fmaf(vv.z, eq[4 * j + 2],
              fmaf(vv.w, eq[4 * j + 3], a))));   // identical nest to verified
        }
        if (even) {
          cur[q] = a;
        } else {
          const float pair = cur[q] + a;                     // even + odd
          run[q] = (cp == 0) ? pair : run[q] + pair;         // ((p0+p1)+p2)+p3
        }
      }
    }
  }

  // ---- scatter scores (swizzled), then per-row argmax (verified order) ----
  if (lane < LROWS) {
#pragma unroll
    for (int q = 0; q < 8; ++q) {
      const int l = wv * 8 + q;
      pacc2[lane * 32 + (l ^ (lane & 7))] = run[q];
    }
  }
  __syncthreads();

  if (tid < LROWS) {
    float bv = -INFINITY;
    int bi = 0;
#pragma unroll
    for (int l = 0; l < 32; ++l) {               // labels ascending, strict >
      const float v = pacc2[tid * 32 + (l ^ (tid & 7))];
      if (v > bv) { bv = v; bi = l; }
    }
    lbl[tid] = bi;
  }
  __syncthreads();   // lbl ready; all raw2/pacc2 reads done -> S4 may overwrite

  // ---- register-stage vis rows (L2-hot re-read) for pooling ----
  float4 r[SROWS / 4 + 3];   // 14
  {
    const int s0 = wv * (SROWS / 4);
#pragma unroll
    for (int j = 0; j < SROWS / 4 + 3; ++j) {
      int t = w0 + s0 + j;
      t = t > (T - 1) ? (T - 1) : t;    // clamp; clamped rows never used
      r[j] = vb[(size_t)t * 64 + lane];
    }
  }

  // ---- majority vote (identical logic, source = LDS lbl) ----
  if (tid < SROWS) {
    const int l0 = lbl[tid], l1 = lbl[tid + 1], l2 = lbl[tid + 2], l3 = lbl[tid + 3];
    const int c0 = 1 + (l0 == l1) + (l0 == l2) + (l0 == l3);
    const int c1 = 1 + (l1 == l0) + (l1 == l2) + (l1 == l3);
    const int c2 = 1 + (l2 == l0) + (l2 == l1) + (l2 == l3);
    const int c3 = 1 + (l3 == l0) + (l3 == l1) + (l3 == l2);
    int best = l0, bc = c0;
    if (c1 > bc || (c1 == bc && l1 < best)) { best = l1; bc = c1; }
    if (c2 > bc || (c2 == bc && l2 < best)) { best = l2; bc = c2; }
    if (c3 > bc || (c3 == bc && l3 < best)) { best = l3; bc = c3; }
    slbl[tid] = best;
  }

  // ---- pooled means into S4 (overlays raw2/pacc2; safe: barrier above) ----
  {
    const int s0 = wv * (SROWS / 4);
#pragma unroll
    for (int s = 0; s < SROWS / 4; ++s) {
      float4 o;
      o.x = (r[s].x + r[s + 1].x + r[s + 2].x + r[s + 3].x) * 0.25f;
      o.y = (r[s].y + r[s + 1].y + r[s + 2].y + r[s + 3].y) * 0.25f;
      o.z = (r[s].z + r[s + 1].z + r[s + 2].z + r[s + 3].z) * 0.25f;
      o.w = (r[s].w + r[s + 1].w + r[s + 2].w + r[s + 3].w) * 0.25f;
      S4[(s0 + s) * 64 + lane] = o;
    }
  }
  __syncthreads();

  // ---- gather enc2 + modulate + nt-store (unchanged) ----
  const float4* e2b = (const float4*)(enc2 + (size_t)b * L * C);
  nfloat4* outp = (nfloat4*)out;
  const int wlim = (NW - w0) < WT ? (NW - w0) : WT;
#pragma unroll
  for (int kk = 0; kk < 2; ++kk) {
    const int k = wv + kk * 4;
#pragma unroll 4
    for (int w = 0; w < wlim; ++w) {
      const int s = w + CIC * k;
      const int lb = slbl[s];                       // LDS broadcast
      const float4 e = e2b[lb * 64 + lane];         // L1/L2-hot (32 KB set)
      const float4 sv = S4[s * 64 + lane];
      nfloat4 o;
      o.x = e.x * sv.x; o.y = e.y * sv.y; o.z = e.z * sv.z; o.w = e.w * sv.w;
      __builtin_nontemporal_store(
          o, &outp[(((size_t)b * NW + w0 + w) * NK + k) * 64 + lane]);
    }
  }
}

extern "C" void kernel_launch(void* const* d_in, const int* in_sizes, int n_in,
                              void* d_out, int out_size, void* d_ws, size_t ws_size,
                              hipStream_t stream) {
  const float* vis   = (const float*)d_in[0];
  const float* query = (const float*)d_in[1];
  const float* W1    = (const float*)d_in[2];
  const float* b1    = (const float*)d_in[3];
  const float* W2    = (const float*)d_in[4];
  const float* b2    = (const float*)d_in[5];
  float* out = (float*)d_out;

  // Workspace: enc1 (64K f), enc2 (64K f) = 512 KB
  float* enc1 = (float*)d_ws;
  float* enc2 = enc1 + (size_t)B * L * C;

  enc_kernel<<<dim3(8, B, 4), 256, 0, stream>>>(query, W1, b1, W2, b2, enc1, enc2);
  fused_kernel<<<dim3((NW + WT - 1) / WT, B), 256, 0, stream>>>(vis, enc1, enc2, out);
}

// Round 6
// 191.656 us; speedup vs baseline: 1.1938x; 1.1938x over previous
//
#include <hip/hip_runtime.h>
#include <hip/hip_bf16.h>

// Problem constants (fixed by setup_inputs)
#define B   8
#define T   2048
#define C   256      // channels; 64 float4
#define L   32       // query rows / label count
#define DQ  512
#define NW  2017     // T - window_size + 1
#define NK  8        // num_chunks
#define CIC 4        // window/num_chunks
#define WT  32       // w-tile per block in out kernel (R0 config)
#define SROWS (WT + (NK-1)*CIC)   // 60 S4 rows per tile
#define LT  32       // t-rows per label block

typedef float nfloat4 __attribute__((ext_vector_type(4)));  // native vec for nt-store

// ---------------- Kernel 1: enc1/enc2 = query @ W{1,2} + b{1,2} ----------------
// (R0 verbatim)
__global__ __launch_bounds__(256) void enc_kernel(
    const float* __restrict__ query, const float* __restrict__ W1,
    const float* __restrict__ b1, const float* __restrict__ W2,
    const float* __restrict__ b2, float* __restrict__ enc1,
    float* __restrict__ enc2) {
  const int lg = blockIdx.x, b = blockIdx.y, cs = blockIdx.z;
  const int tid = threadIdx.x;
  const int tx = tid & 63;    // channel within 64-slice
  const int dq = tid >> 6;    // d-quarter (wave-uniform)
  const int c = cs * 64 + tx;
  __shared__ float4 qs4[4][DQ / 4];        // [j][g] 8 KB
  __shared__ float red[2][4][4][64];       // [e][dq][j][tx] 8 KB

  const float4* q4 = (const float4*)(query + ((size_t)b * L + lg * 4) * DQ);
  for (int i = tid; i < 4 * (DQ / 4); i += 256) {
    const int j = i >> 7, g = i & 127;
    qs4[j][g] = q4[j * (DQ / 4) + g];
  }
  __syncthreads();

  float a1[4] = {0.f, 0.f, 0.f, 0.f};
  float a2[4] = {0.f, 0.f, 0.f, 0.f};
  const int g0 = dq * 32;
#pragma unroll 4
  for (int gg = 0; gg < 32; ++gg) {
    const int g = g0 + gg;
    const float4 q0 = qs4[0][g], q1 = qs4[1][g], q2 = qs4[2][g], q3 = qs4[3][g];
    const float* wp1 = W1 + (size_t)(4 * g) * C + c;
    const float* wp2 = W2 + (size_t)(4 * g) * C + c;
    const float w10 = wp1[0], w11 = wp1[C], w12 = wp1[2 * C], w13 = wp1[3 * C];
    const float w20 = wp2[0], w21 = wp2[C], w22 = wp2[2 * C], w23 = wp2[3 * C];
    a1[0] = fmaf(q0.x, w10, fmaf(q0.y, w11, fmaf(q0.z, w12, fmaf(q0.w, w13, a1[0]))));
    a1[1] = fmaf(q1.x, w10, fmaf(q1.y, w11, fmaf(q1.z, w12, fmaf(q1.w, w13, a1[1]))));
    a1[2] = fmaf(q2.x, w10, fmaf(q2.y, w11, fmaf(q2.z, w12, fmaf(q2.w, w13, a1[2]))));
    a1[3] = fmaf(q3.x, w10, fmaf(q3.y, w11, fmaf(q3.z, w12, fmaf(q3.w, w13, a1[3]))));
    a2[0] = fmaf(q0.x, w20, fmaf(q0.y, w21, fmaf(q0.z, w22, fmaf(q0.w, w23, a2[0]))));
    a2[1] = fmaf(q1.x, w20, fmaf(q1.y, w21, fmaf(q1.z, w22, fmaf(q1.w, w23, a2[1]))));
    a2[2] = fmaf(q2.x, w20, fmaf(q2.y, w21, fmaf(q2.z, w22, fmaf(q2.w, w23, a2[2]))));
    a2[3] = fmaf(q3.x, w20, fmaf(q3.y, w21, fmaf(q3.z, w22, fmaf(q3.w, w23, a2[3]))));
  }
#pragma unroll
  for (int j = 0; j < 4; ++j) {
    red[0][dq][j][tx] = a1[j];
    red[1][dq][j][tx] = a2[j];
  }
  __syncthreads();

  for (int o = tid; o < 512; o += 256) {
    const int e = o >> 8, j = (o >> 6) & 3, t = o & 63;
    const float v = red[e][0][j][t] + red[e][1][j][t] +
                    red[e][2][j][t] + red[e][3][j][t];
    const int cc = cs * 64 + t;
    const size_t off = ((size_t)b * L + lg * 4 + j) * C + cc;
    if (e == 0) enc1[off] = v + b1[cc];
    else        enc2[off] = v + b2[cc];
  }
}

// ---------------- Kernel 2: clip_labels = argmax_l (vis . enc1) ----------------
// Round-6 redesign: outer-product register tiling. Thread = (1 row, 4 labels
// {lg, lg+8, lg+16, lg+24}); both operands come from conflict-free LDS:
//   vis_s [32][65] f4 (row pad -> +4 banks/row: lanes' 8 rows cover 32 banks)
//   e1_s  [32][64] f4, column-rotated by label ((c4+l)&63 -> +4 banks/label:
//         lanes' 8 labels cover 32 banks; 16B alignment preserved)
// vs R0: no pacc LDS round-trip, no 32-thread serial reduce tail, 1 barrier.
// Numerics EXACT vs R0: same per-32ch fmaf nest (w,z,y,x innermost first),
// pair = a_even + a_odd, run = ((p0+p1)+p2)+p3; argmax = max with min-label
// tie-break (tree comparator == R0's ascending strict-> scan).
__global__ __launch_bounds__(256) void label_kernel(
    const float* __restrict__ vis, const float* __restrict__ enc1,
    int* __restrict__ labels) {
  const int b = blockIdx.y;
  const int t0 = blockIdx.x * LT;        // 64 blocks x 32 rows
  const int tid = threadIdx.x;
  const int lg = tid & 7;                // label-group: labels lg + 8q
  const int row = tid >> 3;              // 0..31

  __shared__ float4 vis_s[32 * 65];      // 33280 B
  __shared__ float4 e1_s[32 * 64];       // 32768 B  (total 66 KB -> 2 blocks/CU)

  // stage vis rows t0..t0+31 (coalesced; t0+31 <= 2047, no clamp needed)
  const float4* vb = (const float4*)(vis + (size_t)b * T * C);
  for (int i = tid; i < 32 * 64; i += 256) {
    const int r = i >> 6, c4 = i & 63;
    vis_s[r * 65 + c4] = vb[(size_t)(t0 + r) * 64 + c4];
  }
  // stage enc1 with per-label column rotation
  const float4* e1g = (const float4*)(enc1 + (size_t)b * L * C);
  for (int i = tid; i < 32 * 64; i += 256) {
    const int l = i >> 6, c4 = i & 63;
    e1_s[l * 64 + ((c4 + l) & 63)] = e1g[l * 64 + c4];
  }
  __syncthreads();

  float run[4], cur[4];
#pragma unroll
  for (int cp = 0; cp < 4; ++cp) {       // chunk pairs (64 ch each)
#pragma unroll
    for (int e = 0; e < 2; ++e) {
      const int g = cp * 2 + e;          // 32-ch group, matches R0 "part"
      float a[4] = {0.f, 0.f, 0.f, 0.f};
#pragma unroll
      for (int j = 0; j < 8; ++j) {
        const float4 v = vis_s[row * 65 + g * 8 + j];
#pragma unroll
        for (int q = 0; q < 4; ++q) {
          const int l = lg + 8 * q;
          const float4 ev = e1_s[l * 64 + ((g * 8 + j + l) & 63)];
          a[q] = fmaf(v.x, ev.x,
                 fmaf(v.y, ev.y,
                 fmaf(v.z, ev.z,
                 fmaf(v.w, ev.w, a[q]))));   // identical nest to R0
        }
      }
      if (e == 0) {
#pragma unroll
        for (int q = 0; q < 4; ++q) cur[q] = a[q];
      } else {
#pragma unroll
        for (int q = 0; q < 4; ++q) {
          const float pair = cur[q] + a[q];              // a_even + a_odd
          run[q] = cp ? (run[q] + pair) : pair;          // ((p0+p1)+p2)+p3
        }
      }
    }
  }

  // local argmax over this thread's 4 labels (ascending, strict >)
  float bv = run[0];
  int bl = lg;
#pragma unroll
  for (int q = 1; q < 4; ++q) {
    const int l = lg + 8 * q;
    if (run[q] > bv) { bv = run[q]; bl = l; }
  }
  // tree-reduce across the 8 label-group lanes; min-label wins ties
#pragma unroll
  for (int m = 1; m < 8; m <<= 1) {
    const float ov = __shfl_xor(bv, m, 64);
    const int ol = __shfl_xor(bl, m, 64);
    if (ov > bv || (ov == bv && ol < bl)) { bv = ov; bl = ol; }
  }
  if (lg == 0) labels[(size_t)b * T + t0 + row] = bl;
}

// ---------------- Kernel 3: majority vote + S4 means + modulated output ----------------
// (R0 verbatim)
__global__ __launch_bounds__(256) void out_kernel(
    const float* __restrict__ vis, const float* __restrict__ enc2,
    const int* __restrict__ labels, float* __restrict__ out) {
  const int b = blockIdx.y;
  const int w0 = blockIdx.x * WT;
  const int tid = threadIdx.x;
  const int lane = tid & 63;
  const int wv = tid >> 6;              // wave id, wave-uniform
  __shared__ float4 S4[SROWS * (C / 4)];  // 60 KB, pre-scaled by 0.25
  __shared__ int slbl[SROWS];

  int l0 = 0, l1 = 0, l2 = 0, l3 = 0;
  if (tid < SROWS) {
    const int* lb = labels + (size_t)b * T;
    const int t = w0 + tid;
#define LCL(tt) lb[(tt) > (T - 1) ? (T - 1) : (tt)]
    l0 = LCL(t); l1 = LCL(t + 1); l2 = LCL(t + 2); l3 = LCL(t + 3);
#undef LCL
  }

  const float4* vb = (const float4*)(vis + (size_t)b * T * C);
  float4 r[18];
  {
    const int s0 = wv * (SROWS / 4);
#pragma unroll
    for (int j = 0; j < 18; ++j) {
      int t = w0 + s0 + j;
      t = t > (T - 1) ? (T - 1) : t;    // clamp; clamped rows never used
      r[j] = vb[(size_t)t * (C / 4) + lane];
    }
  }

  if (tid < SROWS) {
    const int c0 = 1 + (l0 == l1) + (l0 == l2) + (l0 == l3);
    const int c1 = 1 + (l1 == l0) + (l1 == l2) + (l1 == l3);
    const int c2 = 1 + (l2 == l0) + (l2 == l1) + (l2 == l3);
    const int c3 = 1 + (l3 == l0) + (l3 == l1) + (l3 == l2);
    int best = l0, bc = c0;
    if (c1 > bc || (c1 == bc && l1 < best)) { best = l1; bc = c1; }
    if (c2 > bc || (c2 == bc && l2 < best)) { best = l2; bc = c2; }
    if (c3 > bc || (c3 == bc && l3 < best)) { best = l3; bc = c3; }
    slbl[tid] = best;
  }

  {
    const int s0 = wv * (SROWS / 4);
#pragma unroll
    for (int s = 0; s < SROWS / 4; ++s) {
      float4 o;
      o.x = (r[s].x + r[s + 1].x + r[s + 2].x + r[s + 3].x) * 0.25f;
      o.y = (r[s].y + r[s + 1].y + r[s + 2].y + r[s + 3].y) * 0.25f;
      o.z = (r[s].z + r[s + 1].z + r[s + 2].z + r[s + 3].z) * 0.25f;
      o.w = (r[s].w + r[s + 1].w + r[s + 2].w + r[s + 3].w) * 0.25f;
      S4[(s0 + s) * (C / 4) + lane] = o;
    }
  }
  __syncthreads();

  const float4* e2b = (const float4*)(enc2 + (size_t)b * L * C);
  nfloat4* outp = (nfloat4*)out;
  const int wlim = (NW - w0) < WT ? (NW - w0) : WT;
#pragma unroll
  for (int kk = 0; kk < 2; ++kk) {
    const int k = wv + kk * 4;
#pragma unroll 4
    for (int w = 0; w < wlim; ++w) {
      const int s = w + CIC * k;
      const int lb = slbl[s];                       // LDS broadcast
      const float4 e = e2b[lb * (C / 4) + lane];    // L1/L2-hot (32 KB set)
      const float4 sv = S4[s * (C / 4) + lane];
      nfloat4 o;
      o.x = e.x * sv.x; o.y = e.y * sv.y; o.z = e.z * sv.z; o.w = e.w * sv.w;
      __builtin_nontemporal_store(
          o, &outp[(((size_t)b * NW + w0 + w) * NK + k) * (C / 4) + lane]);
    }
  }
}

extern "C" void kernel_launch(void* const* d_in, const int* in_sizes, int n_in,
                              void* d_out, int out_size, void* d_ws, size_t ws_size,
                              hipStream_t stream) {
  const float* vis   = (const float*)d_in[0];
  const float* query = (const float*)d_in[1];
  const float* W1    = (const float*)d_in[2];
  const float* b1    = (const float*)d_in[3];
  const float* W2    = (const float*)d_in[4];
  const float* b2    = (const float*)d_in[5];
  float* out = (float*)d_out;

  // Workspace: enc1 (64K f), enc2 (64K f), labels (16K int) = 576 KB
  float* enc1 = (float*)d_ws;
  float* enc2 = enc1 + (size_t)B * L * C;
  int* labels = (int*)(enc2 + (size_t)B * L * C);

  enc_kernel<<<dim3(8, B, 4), 256, 0, stream>>>(query, W1, b1, W2, b2, enc1, enc2);
  label_kernel<<<dim3(T / LT, B), 256, 0, stream>>>(vis, enc1, labels);
  out_kernel<<<dim3((NW + WT - 1) / WT, B), 256, 0, stream>>>(vis, enc2, labels, out);
}

// Round 7
// 187.810 us; speedup vs baseline: 1.2183x; 1.0205x over previous
//
#include <hip/hip_runtime.h>
#include <hip/hip_bf16.h>

// Problem constants (fixed by setup_inputs)
#define B   8
#define T   2048
#define C   256      // channels; 64 float4
#define L   32       // query rows / label count
#define DQ  512
#define NW  2017     // T - window_size + 1
#define NK  8        // num_chunks
#define CIC 4        // window/num_chunks
#define LT  32       // t-rows per label block (R0 config)
#define OWT 16       // w-tile per block in out kernel (R7: halved for occupancy)
#define OSR (OWT + (NK-1)*CIC)    // 44 S4 rows per out tile

typedef float nfloat4 __attribute__((ext_vector_type(4)));  // native vec for nt-store

// ---------------- Kernel 1: enc1/enc2 = query @ W{1,2} + b{1,2} ----------------
// (R0 verbatim)
__global__ __launch_bounds__(256) void enc_kernel(
    const float* __restrict__ query, const float* __restrict__ W1,
    const float* __restrict__ b1, const float* __restrict__ W2,
    const float* __restrict__ b2, float* __restrict__ enc1,
    float* __restrict__ enc2) {
  const int lg = blockIdx.x, b = blockIdx.y, cs = blockIdx.z;
  const int tid = threadIdx.x;
  const int tx = tid & 63;    // channel within 64-slice
  const int dq = tid >> 6;    // d-quarter (wave-uniform)
  const int c = cs * 64 + tx;
  __shared__ float4 qs4[4][DQ / 4];        // [j][g] 8 KB
  __shared__ float red[2][4][4][64];       // [e][dq][j][tx] 8 KB

  const float4* q4 = (const float4*)(query + ((size_t)b * L + lg * 4) * DQ);
  for (int i = tid; i < 4 * (DQ / 4); i += 256) {
    const int j = i >> 7, g = i & 127;
    qs4[j][g] = q4[j * (DQ / 4) + g];
  }
  __syncthreads();

  float a1[4] = {0.f, 0.f, 0.f, 0.f};
  float a2[4] = {0.f, 0.f, 0.f, 0.f};
  const int g0 = dq * 32;
#pragma unroll 4
  for (int gg = 0; gg < 32; ++gg) {
    const int g = g0 + gg;
    const float4 q0 = qs4[0][g], q1 = qs4[1][g], q2 = qs4[2][g], q3 = qs4[3][g];
    const float* wp1 = W1 + (size_t)(4 * g) * C + c;
    const float* wp2 = W2 + (size_t)(4 * g) * C + c;
    const float w10 = wp1[0], w11 = wp1[C], w12 = wp1[2 * C], w13 = wp1[3 * C];
    const float w20 = wp2[0], w21 = wp2[C], w22 = wp2[2 * C], w23 = wp2[3 * C];
    a1[0] = fmaf(q0.x, w10, fmaf(q0.y, w11, fmaf(q0.z, w12, fmaf(q0.w, w13, a1[0]))));
    a1[1] = fmaf(q1.x, w10, fmaf(q1.y, w11, fmaf(q1.z, w12, fmaf(q1.w, w13, a1[1]))));
    a1[2] = fmaf(q2.x, w10, fmaf(q2.y, w11, fmaf(q2.z, w12, fmaf(q2.w, w13, a1[2]))));
    a1[3] = fmaf(q3.x, w10, fmaf(q3.y, w11, fmaf(q3.z, w12, fmaf(q3.w, w13, a1[3]))));
    a2[0] = fmaf(q0.x, w20, fmaf(q0.y, w21, fmaf(q0.z, w22, fmaf(q0.w, w23, a2[0]))));
    a2[1] = fmaf(q1.x, w20, fmaf(q1.y, w21, fmaf(q1.z, w22, fmaf(q1.w, w23, a2[1]))));
    a2[2] = fmaf(q2.x, w20, fmaf(q2.y, w21, fmaf(q2.z, w22, fmaf(q2.w, w23, a2[2]))));
    a2[3] = fmaf(q3.x, w20, fmaf(q3.y, w21, fmaf(q3.z, w22, fmaf(q3.w, w23, a2[3]))));
  }
#pragma unroll
  for (int j = 0; j < 4; ++j) {
    red[0][dq][j][tx] = a1[j];
    red[1][dq][j][tx] = a2[j];
  }
  __syncthreads();

  for (int o = tid; o < 512; o += 256) {
    const int e = o >> 8, j = (o >> 6) & 3, t = o & 63;
    const float v = red[e][0][j][t] + red[e][1][j][t] +
                    red[e][2][j][t] + red[e][3][j][t];
    const int cc = cs * 64 + t;
    const size_t off = ((size_t)b * L + lg * 4 + j) * C + cc;
    if (e == 0) enc1[off] = v + b1[cc];
    else        enc2[off] = v + b2[cc];
  }
}

// ---------------- Kernel 2: clip_labels = argmax_l (vis . enc1) ----------------
// (R0 verbatim — the measured-best label kernel)
__global__ __launch_bounds__(256) void label_kernel(
    const float* __restrict__ vis, const float* __restrict__ enc1,
    int* __restrict__ labels) {
  const int b = blockIdx.y;
  const int t0 = blockIdx.x * LT;
  const int tid = threadIdx.x;
  const int l = tid & 31;     // label row
  const int part = tid >> 5;  // 8-way channel split (32 ch each)
  __shared__ float4 raw[LT * (C / 4)];               // 32 KB
  __shared__ alignas(16) float pacc[4][LT][36];      // 18.4 KB

  float4 ef[8];
  {
    const float4* e1p = (const float4*)(enc1 + ((size_t)b * L + l) * C) + part * 8;
#pragma unroll
    for (int j = 0; j < 8; ++j) ef[j] = e1p[j];   // L2-hot
  }
  const float4* vb = (const float4*)(vis + (size_t)b * T * C);
  for (int i = tid; i < LT * (C / 4); i += 256)
    raw[i] = vb[(size_t)(t0 + (i >> 6)) * (C / 4) + (i & 63)];
  __syncthreads();

  for (int t = 0; t < LT; ++t) {
    const float4* vr = &raw[t * (C / 4) + part * 8];
    float a = 0.f;
#pragma unroll
    for (int j = 0; j < 8; ++j) {
      const float4 v = vr[j];
      a = fmaf(v.x, ef[j].x, fmaf(v.y, ef[j].y, fmaf(v.z, ef[j].z, fmaf(v.w, ef[j].w, a))));
    }
    a += __shfl_down(a, 32);                    // part pair sum (deterministic)
    if (!(tid & 32)) pacc[tid >> 6][t][l] = a;  // banks (4t+l)%32 distinct: free
  }
  __syncthreads();

  if (tid < LT) {
    float4 s4[8];
#pragma unroll
    for (int j = 0; j < 8; ++j) s4[j] = make_float4(0.f, 0.f, 0.f, 0.f);
#pragma unroll
    for (int p = 0; p < 4; ++p) {
      const float4* pp = (const float4*)pacc[p][tid];
#pragma unroll
      for (int j = 0; j < 8; ++j) {
        s4[j].x += pp[j].x; s4[j].y += pp[j].y;
        s4[j].z += pp[j].z; s4[j].w += pp[j].w;
      }
    }
    float bv = -INFINITY;
    int bi = 0;
#pragma unroll
    for (int j = 0; j < 8; ++j) {
      if (s4[j].x > bv) { bv = s4[j].x; bi = 4 * j; }
      if (s4[j].y > bv) { bv = s4[j].y; bi = 4 * j + 1; }
      if (s4[j].z > bv) { bv = s4[j].z; bi = 4 * j + 2; }
      if (s4[j].w > bv) { bv = s4[j].w; bi = 4 * j + 3; }
    }
    labels[(size_t)b * T + t0 + tid] = bi;
  }
}

// ---------------- Kernel 3: majority vote + S4 means + modulated output ----------------
// Round-7: OWT=16 -> 44 KB LDS -> 3 blocks/CU, 1016 blocks (~4 generations):
// one block's store-drain overlaps another's vis-load phase. Full-tile store
// path batches 8x{LDS read + e2b read} before 8 nt-stores for MLP.
// Numerics identical to R0: same pooling groups/order, vote, products, clamps.
__global__ __launch_bounds__(256) void out_kernel(
    const float* __restrict__ vis, const float* __restrict__ enc2,
    const int* __restrict__ labels, float* __restrict__ out) {
  const int b = blockIdx.y;
  const int w0 = blockIdx.x * OWT;
  const int tid = threadIdx.x;
  const int lane = tid & 63;
  const int wv = tid >> 6;              // wave id, wave-uniform
  __shared__ float4 S4[OSR * (C / 4)];  // 44 KB, pre-scaled by 0.25
  __shared__ int slbl[OSR];

  int l0 = 0, l1 = 0, l2 = 0, l3 = 0;
  if (tid < OSR) {
    const int* lb = labels + (size_t)b * T;
    const int t = w0 + tid;
#define LCL(tt) lb[(tt) > (T - 1) ? (T - 1) : (tt)]
    l0 = LCL(t); l1 = LCL(t + 1); l2 = LCL(t + 2); l3 = LCL(t + 3);
#undef LCL
  }

  const float4* vb = (const float4*)(vis + (size_t)b * T * C);
  float4 r[OSR / 4 + 3];                // 14
  {
    const int s0 = wv * (OSR / 4);
#pragma unroll
    for (int j = 0; j < OSR / 4 + 3; ++j) {
      int t = w0 + s0 + j;
      t = t > (T - 1) ? (T - 1) : t;    // clamp; clamped rows never used
      r[j] = vb[(size_t)t * (C / 4) + lane];
    }
  }

  if (tid < OSR) {
    const int c0 = 1 + (l0 == l1) + (l0 == l2) + (l0 == l3);
    const int c1 = 1 + (l1 == l0) + (l1 == l2) + (l1 == l3);
    const int c2 = 1 + (l2 == l0) + (l2 == l1) + (l2 == l3);
    const int c3 = 1 + (l3 == l0) + (l3 == l1) + (l3 == l2);
    int best = l0, bc = c0;
    if (c1 > bc || (c1 == bc && l1 < best)) { best = l1; bc = c1; }
    if (c2 > bc || (c2 == bc && l2 < best)) { best = l2; bc = c2; }
    if (c3 > bc || (c3 == bc && l3 < best)) { best = l3; bc = c3; }
    slbl[tid] = best;
  }

  {
    const int s0 = wv * (OSR / 4);
#pragma unroll
    for (int s = 0; s < OSR / 4; ++s) {
      float4 o;
      o.x = (r[s].x + r[s + 1].x + r[s + 2].x + r[s + 3].x) * 0.25f;
      o.y = (r[s].y + r[s + 1].y + r[s + 2].y + r[s + 3].y) * 0.25f;
      o.z = (r[s].z + r[s + 1].z + r[s + 2].z + r[s + 3].z) * 0.25f;
      o.w = (r[s].w + r[s + 1].w + r[s + 2].w + r[s + 3].w) * 0.25f;
      S4[(s0 + s) * (C / 4) + lane] = o;
    }
  }
  __syncthreads();

  const float4* e2b = (const float4*)(enc2 + (size_t)b * L * C);
  nfloat4* outp = (nfloat4*)out;
  const int wlim = (NW - w0) < OWT ? (NW - w0) : OWT;

  if (wlim == OWT) {
    // full tile: batched loads-then-stores, compile-time trip counts
#pragma unroll
    for (int kk = 0; kk < 2; ++kk) {
      const int k = wv + kk * 4;
      const size_t obase = (((size_t)b * NW + w0) * NK + k) * (C / 4) + lane;
#pragma unroll
      for (int h = 0; h < 2; ++h) {          // halves of 8 w's
        float4 ee[8], ss[8];
#pragma unroll
        for (int i = 0; i < 8; ++i) {
          const int s = (h * 8 + i) + CIC * k;
          ss[i] = S4[s * (C / 4) + lane];
          ee[i] = e2b[slbl[s] * (C / 4) + lane];
        }
#pragma unroll
        for (int i = 0; i < 8; ++i) {
          nfloat4 o;
          o.x = ee[i].x * ss[i].x; o.y = ee[i].y * ss[i].y;
          o.z = ee[i].z * ss[i].z; o.w = ee[i].w * ss[i].w;
          __builtin_nontemporal_store(o, &outp[obase + (size_t)(h * 8 + i) * NK * (C / 4)]);
        }
      }
    }
  } else {
    // tail tile (w0 = 2016, wlim = 1)
#pragma unroll
    for (int kk = 0; kk < 2; ++kk) {
      const int k = wv + kk * 4;
      for (int w = 0; w < wlim; ++w) {
        const int s = w + CIC * k;
        const int lb = slbl[s];
        const float4 e = e2b[lb * (C / 4) + lane];
        const float4 sv = S4[s * (C / 4) + lane];
        nfloat4 o;
        o.x = e.x * sv.x; o.y = e.y * sv.y; o.z = e.z * sv.z; o.w = e.w * sv.w;
        __builtin_nontemporal_store(
            o, &outp[(((size_t)b * NW + w0 + w) * NK + k) * (C / 4) + lane]);
      }
    }
  }
}

extern "C" void kernel_launch(void* const* d_in, const int* in_sizes, int n_in,
                              void* d_out, int out_size, void* d_ws, size_t ws_size,
                              hipStream_t stream) {
  const float* vis   = (const float*)d_in[0];
  const float* query = (const float*)d_in[1];
  const float* W1    = (const float*)d_in[2];
  const float* b1    = (const float*)d_in[3];
  const float* W2    = (const float*)d_in[4];
  const float* b2    = (const float*)d_in[5];
  float* out = (float*)d_out;

  // Workspace: enc1 (64K f), enc2 (64K f), labels (16K int) = 576 KB
  float* enc1 = (float*)d_ws;
  float* enc2 = enc1 + (size_t)B * L * C;
  int* labels = (int*)(enc2 + (size_t)B * L * C);

  enc_kernel<<<dim3(8, B, 4), 256, 0, stream>>>(query, W1, b1, W2, b2, enc1, enc2);
  label_kernel<<<dim3(T / LT, B), 256, 0, stream>>>(vis, enc1, labels);
  out_kernel<<<dim3((NW + OWT - 1) / OWT, B), 256, 0, stream>>>(vis, enc2, labels, out);
}